// Round 1
// baseline (123.394 us; speedup 1.0000x reference)
//
#include <hip/hip_runtime.h>

// Composite-filter formulation:
//   out[o] = sum_{k=0..54} Cp[r][k] * x[n0 - k],
//     r = (2o+32) % 3, n0 = (2o+32-r)/3,
//     Cp[p][k] = C[p+3k], C[j] = sum_m b[m]*h[j-2m]
// fused_fast covers 50 <= o < n_out; boundary kernel covers o<50 and o>=n_out.
//
// R6 post-mortem: loads pinned, fused ~37us, L1-BW-bound (40 B L1/output).
// R7: RPT=12 -> 16 window chunks per 12 outputs (21 B/output).
// R8 post-mortem of R7: VALUBusy=22%, HBM=18% -> NOT VALU-floor; latency-bound.
//   One-shot blocks pay full load latency + launch overhead per 12 outputs.
// R8: persistent kernel, 4 tiles/block, double-buffered register window
//   (wA/wB, 2x64 VGPR). Next tile's 16 global loads issue BEFORE the current
//   tile's 660-FMA stream, so L2/L3 latency hides under compute. Prologue
//   latency amortized 4x. Edge tiles (first/last) keep the LDS staged path.

#define TPB 256
#define RPT 12                    // outputs per thread
#define OTILE (TPB * RPT)         // 3072 outputs per tile
#define TPBLK 4                   // tiles per block (persistent loop, unrolled)
#define XTILE2 2112               // edge-path staging (needs 2104)
#define NTAPS 55
#define CPSTRIDE 56               // phase-major coeff stride (zero-padded, float4-aligned)

__global__ void build_coeffs(const float* __restrict__ h,
                             const float* __restrict__ b,
                             float* __restrict__ cp) {
    __shared__ float h_s[63];
    __shared__ float b_s[51];
    const int tid = threadIdx.x;
    if (tid < 63) h_s[tid] = h[tid];
    if (tid < 51) b_s[tid] = b[tid];
    __syncthreads();
    for (int idx = tid; idx < 3 * CPSTRIDE; idx += blockDim.x) {
        const int p = idx / CPSTRIDE;
        const int k = idx - p * CPSTRIDE;
        float acc = 0.0f;
        if (k < NTAPS) {
            const int j = p + 3 * k;
            for (int m = 0; m <= 50; ++m) {
                const int hi = j - 2 * m;
                if (hi >= 0 && hi <= 62) acc += b_s[m] * h_s[hi];
            }
        }
        cp[idx] = acc;
    }
}

// Block 0 = head (o in [0,50)), block 1 = tail (o in [n_out, out_size)).
__global__ __launch_bounds__(128) void boundary_fix(
    const float* __restrict__ x, const float* __restrict__ h,
    const float* __restrict__ b, float* __restrict__ out,
    int n_in, int n_out, int out_size)
{
    __shared__ float h_s[63];
    __shared__ float b_s[51];
    __shared__ float x_s[64];
    __shared__ float u_s[50];

    const int tid = threadIdx.x;
    if (tid < 63) h_s[tid] = h[tid];
    if (tid < 51) b_s[tid] = b[tid];

    if (blockIdx.x == 0) {
        if (tid < 44) x_s[tid] = (tid < n_in) ? x[tid] : 0.0f;
        __syncthreads();
        if (tid < 50) {
            const int s  = 2 * tid + 32;
            const int p0 = s % 3;
            const int q  = s / 3;
            float u = 0.0f;
            #pragma unroll
            for (int i = 0; i <= 20; ++i) {
                const int xi = q - i;
                u += h_s[p0 + 3 * i] * ((xi >= 0) ? x_s[xi] : 0.0f);
            }
            u_s[tid] = u;
        }
        __syncthreads();
        if (tid < 50) {
            float acc = 0.0f;
            for (int t = 0; t <= tid; ++t) acc += b_s[tid - t] * u_s[t];
            out[tid] = acc;
        }
    } else {
        const int t0   = n_out - 50;
        const int qmin = (2 * t0 + 32) / 3;
        const int xb   = qmin - 20;
        if (tid < 64) {
            const int xi = xb + tid;
            x_s[tid] = (xi >= 0 && xi < n_in) ? x[xi] : 0.0f;
        }
        __syncthreads();
        if (tid < 50) {
            const int t  = t0 + tid;
            const int s  = 2 * t + 32;
            const int p0 = s % 3;
            const int q  = s / 3;
            const int base = q - xb;
            float u = 0.0f;
            #pragma unroll
            for (int i = 0; i <= 20; ++i)
                u += h_s[p0 + 3 * i] * x_s[base - i];
            u_s[tid] = u;
        }
        __syncthreads();
        const int n_tail = out_size - n_out;   // 96
        if (tid < n_tail) {
            float acc = 0.0f;
            for (int j = tid; j <= 49; ++j) acc += b_s[tid + 50 - j] * u_s[j];
            out[n_out + tid] = acc;
        }
    }
}

// Group g covers taps k=4g..4g+3 for 12 outputs d=0..11.
// delta_d = {0,1,2,2,3,4,4,5,6,6,7,8}, phase r_d = (2+2d)%3 -> q2/q1/q0 cycle.
// Window float (54+delta-4g-j) -> chunks: A=w[15-g], B=w[14-g], C=w[13-g], D=w[12-g].
#define GRP12(g, A, B, C, D) {                                          \
    const float4 q2 = c2q[g];                                           \
    const float4 q1 = c1q[g];                                           \
    const float4 q0 = c0q[g];                                           \
    /* j=0 */                                                           \
    a0  += q2.x * C.z;  a1  += q1.x * C.w;  a2  += q0.x * B.x;          \
    a3  += q2.x * B.x;  a4  += q1.x * B.y;  a5  += q0.x * B.z;          \
    a6  += q2.x * B.z;  a7  += q1.x * B.w;  a8  += q0.x * A.x;          \
    a9  += q2.x * A.x;  a10 += q1.x * A.y;  a11 += q0.x * A.z;          \
    /* j=1 */                                                           \
    a0  += q2.y * C.y;  a1  += q1.y * C.z;  a2  += q0.y * C.w;          \
    a3  += q2.y * C.w;  a4  += q1.y * B.x;  a5  += q0.y * B.y;          \
    a6  += q2.y * B.y;  a7  += q1.y * B.z;  a8  += q0.y * B.w;          \
    a9  += q2.y * B.w;  a10 += q1.y * A.x;  a11 += q0.y * A.y;          \
    /* j=2 */                                                           \
    a0  += q2.z * C.x;  a1  += q1.z * C.y;  a2  += q0.z * C.z;          \
    a3  += q2.z * C.z;  a4  += q1.z * C.w;  a5  += q0.z * B.x;          \
    a6  += q2.z * B.x;  a7  += q1.z * B.y;  a8  += q0.z * B.z;          \
    a9  += q2.z * B.z;  a10 += q1.z * B.w;  a11 += q0.z * A.x;          \
    /* j=3 */                                                           \
    a0  += q2.w * D.w;  a1  += q1.w * C.x;  a2  += q0.w * C.y;          \
    a3  += q2.w * C.y;  a4  += q1.w * C.z;  a5  += q0.w * C.w;          \
    a6  += q2.w * C.w;  a7  += q1.w * B.x;  a8  += q0.w * B.y;          \
    a9  += q2.w * B.y;  a10 += q1.w * B.z;  a11 += q0.w * B.w; }

// Tail group: j=0..2 only (k = 52,53,54).
#define GRP12T(g, A, B, C) {                                            \
    const float4 q2 = c2q[g];                                           \
    const float4 q1 = c1q[g];                                           \
    const float4 q0 = c0q[g];                                           \
    a0  += q2.x * C.z;  a1  += q1.x * C.w;  a2  += q0.x * B.x;          \
    a3  += q2.x * B.x;  a4  += q1.x * B.y;  a5  += q0.x * B.z;          \
    a6  += q2.x * B.z;  a7  += q1.x * B.w;  a8  += q0.x * A.x;          \
    a9  += q2.x * A.x;  a10 += q1.x * A.y;  a11 += q0.x * A.z;          \
    a0  += q2.y * C.y;  a1  += q1.y * C.z;  a2  += q0.y * C.w;          \
    a3  += q2.y * C.w;  a4  += q1.y * B.x;  a5  += q0.y * B.y;          \
    a6  += q2.y * B.y;  a7  += q1.y * B.z;  a8  += q0.y * B.w;          \
    a9  += q2.y * B.w;  a10 += q1.y * A.x;  a11 += q0.y * A.y;          \
    a0  += q2.z * C.x;  a1  += q1.z * C.y;  a2  += q0.z * C.z;          \
    a3  += q2.z * C.z;  a4  += q1.z * C.w;  a5  += q0.z * B.x;          \
    a6  += q2.z * B.x;  a7  += q1.z * B.y;  a8  += q0.z * B.z;          \
    a9  += q2.z * B.z;  a10 += q1.z * B.w;  a11 += q0.z * A.x; }

// --- R8: named double-buffer window machinery -------------------------------
#define DECLW(S)                                                        \
    float4 S##15, S##14, S##13, S##12, S##11, S##10, S##9, S##8,        \
           S##7,  S##6,  S##5,  S##4,  S##3,  S##2,  S##1,  S##0;

// Issue all 16 chunk loads (w15 first = first consumed).
#define LOADW(S, SRC) {                                                 \
    S##15 = SRC[15]; S##14 = SRC[14]; S##13 = SRC[13]; S##12 = SRC[12]; \
    S##11 = SRC[11]; S##10 = SRC[10]; S##9  = SRC[9];  S##8  = SRC[8];  \
    S##7  = SRC[7];  S##6  = SRC[6];  S##5  = SRC[5];  S##4  = SRC[4];  \
    S##3  = SRC[3];  S##2  = SRC[2];  S##1  = SRC[1];  S##0  = SRC[0]; }

// Pure 660-FMA stream on a named window set (loads already in flight).
#define CONVW(S) {                                                      \
    GRP12( 0, S##15, S##14, S##13, S##12);                              \
    GRP12( 1, S##14, S##13, S##12, S##11);                              \
    GRP12( 2, S##13, S##12, S##11, S##10);                              \
    GRP12( 3, S##12, S##11, S##10, S##9);                               \
    GRP12( 4, S##11, S##10, S##9,  S##8);                               \
    GRP12( 5, S##10, S##9,  S##8,  S##7);                               \
    GRP12( 6, S##9,  S##8,  S##7,  S##6);                               \
    GRP12( 7, S##8,  S##7,  S##6,  S##5);                               \
    GRP12( 8, S##7,  S##6,  S##5,  S##4);                               \
    GRP12( 9, S##6,  S##5,  S##4,  S##3);                               \
    GRP12(10, S##5,  S##4,  S##3,  S##2);                               \
    GRP12(11, S##4,  S##3,  S##2,  S##1);                               \
    GRP12(12, S##3,  S##2,  S##1,  S##0);                               \
    GRP12T(13, S##2, S##1, S##0); }

// Legacy single-shot path (LDS edge tiles): load + pin + FMA.
#define CONV12(SRC) {                                                   \
    const float4 w15 = SRC[15]; const float4 w14 = SRC[14];             \
    const float4 w13 = SRC[13]; const float4 w12 = SRC[12];             \
    const float4 w11 = SRC[11]; const float4 w10 = SRC[10];             \
    const float4 w9  = SRC[9];  const float4 w8  = SRC[8];              \
    const float4 w7  = SRC[7];  const float4 w6  = SRC[6];              \
    const float4 w5  = SRC[5];  const float4 w4  = SRC[4];              \
    const float4 w3  = SRC[3];  const float4 w2  = SRC[2];              \
    const float4 w1  = SRC[1];  const float4 w0  = SRC[0];              \
    __builtin_amdgcn_sched_barrier(0);                                  \
    GRP12( 0, w15, w14, w13, w12);                                      \
    GRP12( 1, w14, w13, w12, w11);                                      \
    GRP12( 2, w13, w12, w11, w10);                                      \
    GRP12( 3, w12, w11, w10, w9);                                       \
    GRP12( 4, w11, w10, w9,  w8);                                       \
    GRP12( 5, w10, w9,  w8,  w7);                                       \
    GRP12( 6, w9,  w8,  w7,  w6);                                       \
    GRP12( 7, w8,  w7,  w6,  w5);                                       \
    GRP12( 8, w7,  w6,  w5,  w4);                                       \
    GRP12( 9, w6,  w5,  w4,  w3);                                       \
    GRP12(10, w5,  w4,  w3,  w2);                                       \
    GRP12(11, w4,  w3,  w2,  w1);                                       \
    GRP12(12, w3,  w2,  w1,  w0);                                       \
    GRP12T(13, w2, w1, w0); }

// Rare path: tiles touching x boundaries (exactly first + last tile).
// Block-uniform branch, so __syncthreads is safe.
#define EDGE_COMPUTE(NT0) {                                             \
    __syncthreads();                                                    \
    for (int i = tid; i < XTILE2; i += TPB) {                           \
        const int n = (NT0) + i;                                        \
        x_s[i] = (n >= 0 && n < n_in) ? x[n] : 0.0f;                    \
    }                                                                   \
    __syncthreads();                                                    \
    const float4* xs4 = (const float4*)(x_s) + 2 * tid;                 \
    CONV12(xs4); }

#define ZERO_ACC() { a0=0.f;a1=0.f;a2=0.f;a3=0.f;a4=0.f;a5=0.f;        \
                     a6=0.f;a7=0.f;a8=0.f;a9=0.f;a10=0.f;a11=0.f; }

#define STORE12(OB) {                                                   \
    const int ob_ = (OB);                                               \
    if (ob_ >= 50 && ob_ + 11 < n_out) {                                \
        float4* o4 = (float4*)(out + ob_);  /* 16B aligned (ob%4==0) */ \
        o4[0] = make_float4(a0, a1, a2,  a3);                           \
        o4[1] = make_float4(a4, a5, a6,  a7);                           \
        o4[2] = make_float4(a8, a9, a10, a11);                          \
    } else {                                                            \
        const float accs[RPT] = {a0,a1,a2,a3,a4,a5,a6,a7,a8,a9,a10,a11};\
        _Pragma("unroll")                                               \
        for (int d = 0; d < RPT; ++d) {                                 \
            const int o = ob_ + d;                                      \
            if (o >= 50 && o < n_out) out[o] = accs[d];                 \
        }                                                               \
    } }

__global__ __launch_bounds__(TPB) void fused_fast(
    const float* __restrict__ x, const float* __restrict__ cp,
    float* __restrict__ out, int n_in, int n_out, int ntiles)
{
    __shared__ float x_s[XTILE2];

    const int tid = threadIdx.x;

    const float4* c2q = (const float4*)(cp + 2 * CPSTRIDE);  // phase 2 (o%3==0)
    const float4* c1q = (const float4*)(cp + 1 * CPSTRIDE);
    const float4* c0q = (const float4*)(cp + 0 * CPSTRIDE);

    // 4 consecutive tiles per block: bt = blockIdx.x*4 + t.
    // Per tile: o0 = bt*3072, Qb = 2048*bt + 10, n_tile0 = 2048*bt - 44
    // (multiple of 4 -> every thread's window base 16B-aligned).
    const int bt_0 = blockIdx.x * TPBLK;
    const int bt_1 = bt_0 + 1;
    const int bt_2 = bt_0 + 2;
    const int bt_3 = bt_0 + 3;

    const int nt0_0 = 2048 * bt_0 - 44;
    const int nt0_1 = 2048 * bt_1 - 44;
    const int nt0_2 = 2048 * bt_2 - 44;
    const int nt0_3 = 2048 * bt_3 - 44;

    const bool v0 = bt_0 < ntiles;
    const bool v1 = bt_1 < ntiles;
    const bool v2 = bt_2 < ntiles;
    const bool v3 = bt_3 < ntiles;

    // interior: [n_tile0, Qb+2049] within [0, n_in)  <=>  nt0>=0 && 2048*bt+2060<=n_in
    const bool i0 = v0 && (nt0_0 >= 0) && (2048 * bt_0 + 2060 <= n_in);
    const bool i1 = v1 && (nt0_1 >= 0) && (2048 * bt_1 + 2060 <= n_in);
    const bool i2 = v2 && (nt0_2 >= 0) && (2048 * bt_2 + 2060 <= n_in);
    const bool i3 = v3 && (nt0_3 >= 0) && (2048 * bt_3 + 2060 <= n_in);

    const float4* s0 = (const float4*)(x + nt0_0 + 8 * tid);
    const float4* s1 = (const float4*)(x + nt0_1 + 8 * tid);
    const float4* s2 = (const float4*)(x + nt0_2 + 8 * tid);
    const float4* s3 = (const float4*)(x + nt0_3 + 8 * tid);

    DECLW(wA)
    DECLW(wB)
    float a0, a1, a2, a3, a4, a5, a6, a7, a8, a9, a10, a11;

    // ---- prologue: prefetch tile 0 into A ----
    if (i0) LOADW(wA, s0);
    __builtin_amdgcn_sched_barrier(0);

    // ---- tile 0: prefetch tile 1 into B, compute A ----
    if (i1) LOADW(wB, s1);
    __builtin_amdgcn_sched_barrier(0);
    if (v0) {
        ZERO_ACC();
        if (i0) { CONVW(wA); }
        else    { EDGE_COMPUTE(nt0_0); }
        STORE12(bt_0 * OTILE + RPT * tid);
    }

    // ---- tile 1: prefetch tile 2 into A (WAR after CONVW(wA)), compute B ----
    if (i2) LOADW(wA, s2);
    __builtin_amdgcn_sched_barrier(0);
    if (v1) {
        ZERO_ACC();
        if (i1) { CONVW(wB); }
        else    { EDGE_COMPUTE(nt0_1); }
        STORE12(bt_1 * OTILE + RPT * tid);
    }

    // ---- tile 2: prefetch tile 3 into B, compute A ----
    if (i3) LOADW(wB, s3);
    __builtin_amdgcn_sched_barrier(0);
    if (v2) {
        ZERO_ACC();
        if (i2) { CONVW(wA); }
        else    { EDGE_COMPUTE(nt0_2); }
        STORE12(bt_2 * OTILE + RPT * tid);
    }

    // ---- tile 3: compute B (no more prefetch) ----
    if (v3) {
        ZERO_ACC();
        if (i3) { CONVW(wB); }
        else    { EDGE_COMPUTE(nt0_3); }
        STORE12(bt_3 * OTILE + RPT * tid);
    }
}

extern "C" void kernel_launch(void* const* d_in, const int* in_sizes, int n_in_arrs,
                              void* d_out, int out_size, void* d_ws, size_t ws_size,
                              hipStream_t stream) {
    const float* x = (const float*)d_in[0];
    const float* h = (const float*)d_in[1];
    const float* b = (const float*)d_in[2];
    float* out = (float*)d_out;
    float* cp  = (float*)d_ws;                        // 3*56*4 = 672 bytes

    const int n_in  = in_sizes[0];                    // 8388608
    const int n_out = (int)((long long)n_in * 3 / 2); // 12582912

    build_coeffs<<<1, 64, 0, stream>>>(h, b, cp);

    const int ntiles  = (n_out + OTILE - 1) / OTILE;         // 4096
    const int nblocks = (ntiles + TPBLK - 1) / TPBLK;        // 1024
    fused_fast<<<nblocks, TPB, 0, stream>>>(x, cp, out, n_in, n_out, ntiles);
    boundary_fix<<<2, 128, 0, stream>>>(x, h, b, out, n_in, n_out, out_size);
}

// Round 2
// 116.987 us; speedup vs baseline: 1.0548x; 1.0548x over previous
//
#include <hip/hip_runtime.h>

// Composite-filter formulation:
//   out[o] = sum_{k=0..54} Cp[r][k] * x[n0 - k],
//     r = (2o+32) % 3, n0 = (2o+32-r)/3,
//     Cp[p][k] = C[p+3k], C[j] = sum_m b[m]*h[j-2m]
// fused_fast covers 50 <= o < n_out; boundary kernel covers o<50 and o>=n_out.
//
// R7: direct-global windows, RPT=12. 46us, VALUBusy 22%, HBM 18% -> stalled.
// R8 FAILED: persistent + reg double-buffer: VGPR 128, occupancy halved, 77us.
//   Lesson: latency hiding here comes from TLP (8 waves/SIMD at ~44 VGPR).
// R9: back to 4096 one-tile blocks. Theory: R7 was L1/TCP-bound -- 16 strided
//   dwordx4/thread, each spanning ~17 lines/wave, 8x re-read of every chunk.
//   Stage the 8.4KB tile in LDS once (2 coalesced loads/thread), read windows
//   from LDS with an XOR float4-slot swizzle slot(c)=c^((c>>3)&7):
//   stride-2 reads then spread 8 addresses over each 4-bank group = the
//   1024B/128B = 8-cycle minimum (conflict-optimal). Compute keeps a 6-reg
//   rotating window (distance-2 prefetch) so VGPR stays low -> 8 waves/SIMD.

#define TPB 256
#define RPT 12                    // outputs per thread
#define OTILE (TPB * RPT)         // 3072 outputs per block
#define NCHUNK 528                // float4 chunks staged per tile (2112 floats)
#define NTAPS 55
#define CPSTRIDE 56               // phase-major coeff stride (zero-padded, float4-aligned)

#define SLOT(c) ((c) ^ (((c) >> 3) & 7))

__global__ void build_coeffs(const float* __restrict__ h,
                             const float* __restrict__ b,
                             float* __restrict__ cp) {
    __shared__ float h_s[63];
    __shared__ float b_s[51];
    const int tid = threadIdx.x;
    if (tid < 63) h_s[tid] = h[tid];
    if (tid < 51) b_s[tid] = b[tid];
    __syncthreads();
    for (int idx = tid; idx < 3 * CPSTRIDE; idx += blockDim.x) {
        const int p = idx / CPSTRIDE;
        const int k = idx - p * CPSTRIDE;
        float acc = 0.0f;
        if (k < NTAPS) {
            const int j = p + 3 * k;
            for (int m = 0; m <= 50; ++m) {
                const int hi = j - 2 * m;
                if (hi >= 0 && hi <= 62) acc += b_s[m] * h_s[hi];
            }
        }
        cp[idx] = acc;
    }
}

// Block 0 = head (o in [0,50)), block 1 = tail (o in [n_out, out_size)).
__global__ __launch_bounds__(128) void boundary_fix(
    const float* __restrict__ x, const float* __restrict__ h,
    const float* __restrict__ b, float* __restrict__ out,
    int n_in, int n_out, int out_size)
{
    __shared__ float h_s[63];
    __shared__ float b_s[51];
    __shared__ float x_s[64];
    __shared__ float u_s[50];

    const int tid = threadIdx.x;
    if (tid < 63) h_s[tid] = h[tid];
    if (tid < 51) b_s[tid] = b[tid];

    if (blockIdx.x == 0) {
        if (tid < 44) x_s[tid] = (tid < n_in) ? x[tid] : 0.0f;
        __syncthreads();
        if (tid < 50) {
            const int s  = 2 * tid + 32;
            const int p0 = s % 3;
            const int q  = s / 3;
            float u = 0.0f;
            #pragma unroll
            for (int i = 0; i <= 20; ++i) {
                const int xi = q - i;
                u += h_s[p0 + 3 * i] * ((xi >= 0) ? x_s[xi] : 0.0f);
            }
            u_s[tid] = u;
        }
        __syncthreads();
        if (tid < 50) {
            float acc = 0.0f;
            for (int t = 0; t <= tid; ++t) acc += b_s[tid - t] * u_s[t];
            out[tid] = acc;
        }
    } else {
        const int t0   = n_out - 50;
        const int qmin = (2 * t0 + 32) / 3;
        const int xb   = qmin - 20;
        if (tid < 64) {
            const int xi = xb + tid;
            x_s[tid] = (xi >= 0 && xi < n_in) ? x[xi] : 0.0f;
        }
        __syncthreads();
        if (tid < 50) {
            const int t  = t0 + tid;
            const int s  = 2 * t + 32;
            const int p0 = s % 3;
            const int q  = s / 3;
            const int base = q - xb;
            float u = 0.0f;
            #pragma unroll
            for (int i = 0; i <= 20; ++i)
                u += h_s[p0 + 3 * i] * x_s[base - i];
            u_s[tid] = u;
        }
        __syncthreads();
        const int n_tail = out_size - n_out;   // 96
        if (tid < n_tail) {
            float acc = 0.0f;
            for (int j = tid; j <= 49; ++j) acc += b_s[tid + 50 - j] * u_s[j];
            out[n_out + tid] = acc;
        }
    }
}

// Group g covers taps k=4g..4g+3 for 12 outputs d=0..11.
// delta_d = {0,1,2,2,3,4,4,5,6,6,7,8}, phase r_d = (2+2d)%3 -> q2/q1/q0 cycle.
// Window float (54+delta-4g-j) -> chunks: A=w[15-g], B=w[14-g], C=w[13-g], D=w[12-g].
#define GRP12(g, A, B, C, D) {                                          \
    const float4 q2 = c2q[g];                                           \
    const float4 q1 = c1q[g];                                           \
    const float4 q0 = c0q[g];                                           \
    /* j=0 */                                                           \
    a0  += q2.x * C.z;  a1  += q1.x * C.w;  a2  += q0.x * B.x;          \
    a3  += q2.x * B.x;  a4  += q1.x * B.y;  a5  += q0.x * B.z;          \
    a6  += q2.x * B.z;  a7  += q1.x * B.w;  a8  += q0.x * A.x;          \
    a9  += q2.x * A.x;  a10 += q1.x * A.y;  a11 += q0.x * A.z;          \
    /* j=1 */                                                           \
    a0  += q2.y * C.y;  a1  += q1.y * C.z;  a2  += q0.y * C.w;          \
    a3  += q2.y * C.w;  a4  += q1.y * B.x;  a5  += q0.y * B.y;          \
    a6  += q2.y * B.y;  a7  += q1.y * B.z;  a8  += q0.y * B.w;          \
    a9  += q2.y * B.w;  a10 += q1.y * A.x;  a11 += q0.y * A.y;          \
    /* j=2 */                                                           \
    a0  += q2.z * C.x;  a1  += q1.z * C.y;  a2  += q0.z * C.z;          \
    a3  += q2.z * C.z;  a4  += q1.z * C.w;  a5  += q0.z * B.x;          \
    a6  += q2.z * B.x;  a7  += q1.z * B.y;  a8  += q0.z * B.z;          \
    a9  += q2.z * B.z;  a10 += q1.z * B.w;  a11 += q0.z * A.x;          \
    /* j=3 */                                                           \
    a0  += q2.w * D.w;  a1  += q1.w * C.x;  a2  += q0.w * C.y;          \
    a3  += q2.w * C.y;  a4  += q1.w * C.z;  a5  += q0.w * C.w;          \
    a6  += q2.w * C.w;  a7  += q1.w * B.x;  a8  += q0.w * B.y;          \
    a9  += q2.w * B.y;  a10 += q1.w * B.z;  a11 += q0.w * B.w; }

// Tail group: j=0..2 only (k = 52,53,54).
#define GRP12T(g, A, B, C) {                                            \
    const float4 q2 = c2q[g];                                           \
    const float4 q1 = c1q[g];                                           \
    const float4 q0 = c0q[g];                                           \
    a0  += q2.x * C.z;  a1  += q1.x * C.w;  a2  += q0.x * B.x;          \
    a3  += q2.x * B.x;  a4  += q1.x * B.y;  a5  += q0.x * B.z;          \
    a6  += q2.x * B.z;  a7  += q1.x * B.w;  a8  += q0.x * A.x;          \
    a9  += q2.x * A.x;  a10 += q1.x * A.y;  a11 += q0.x * A.z;          \
    a0  += q2.y * C.y;  a1  += q1.y * C.z;  a2  += q0.y * C.w;          \
    a3  += q2.y * C.w;  a4  += q1.y * B.x;  a5  += q0.y * B.y;          \
    a6  += q2.y * B.y;  a7  += q1.y * B.z;  a8  += q0.y * B.w;          \
    a9  += q2.y * B.w;  a10 += q1.y * A.x;  a11 += q0.y * A.y;          \
    a0  += q2.z * C.x;  a1  += q1.z * C.y;  a2  += q0.z * C.z;          \
    a3  += q2.z * C.z;  a4  += q1.z * C.w;  a5  += q0.z * B.x;          \
    a6  += q2.z * B.x;  a7  += q1.z * B.y;  a8  += q0.z * B.z;          \
    a9  += q2.z * B.z;  a10 += q1.z * B.w;  a11 += q0.z * A.x; }

__global__ __launch_bounds__(TPB) void fused_fast(
    const float* __restrict__ x, const float* __restrict__ cp,
    float* __restrict__ out, int n_in, int n_out)
{
    __shared__ float4 xs4[NCHUNK];   // 8448 B, XOR-swizzled float4 slots

    const int tid = threadIdx.x;
    const int bt  = blockIdx.x;
    const int o0  = bt * OTILE;                  // multiple of 3072
    const int n_tile0 = 2048 * bt - 44;          // tile x-base, multiple of 4

    const float4* c2q = (const float4*)(cp + 2 * CPSTRIDE);  // phase 2 (o%3==0)
    const float4* c1q = (const float4*)(cp + 1 * CPSTRIDE);
    const float4* c0q = (const float4*)(cp + 0 * CPSTRIDE);

    // ---- stage tile into LDS (swizzled slots) ----
    // interior: staging reads [n_tile0, n_tile0 + 2112) fully inside x
    const bool interior = (n_tile0 >= 0) && (n_tile0 + 4 * NCHUNK <= n_in);
    if (interior) {
        const float4* gx = (const float4*)(x + n_tile0);
        const float4 g0 = gx[tid];
        const float4 g1 = gx[tid + 256];
        xs4[SLOT(tid)]       = g0;
        xs4[SLOT(tid + 256)] = g1;
        if (tid < NCHUNK - 512) {
            xs4[SLOT(tid + 512)] = gx[tid + 512];
        }
    } else {
        float* xsf = (float*)xs4;
        for (int i = tid; i < 4 * NCHUNK; i += TPB) {
            const int n = n_tile0 + i;
            const float v = (n >= 0 && n < n_in) ? x[n] : 0.0f;
            xsf[(SLOT(i >> 2) << 2) | (i & 3)] = v;
        }
    }
    __syncthreads();

    float a0 = 0.f, a1 = 0.f, a2 = 0.f, a3  = 0.f, a4  = 0.f, a5  = 0.f;
    float a6 = 0.f, a7 = 0.f, a8 = 0.f, a9  = 0.f, a10 = 0.f, a11 = 0.f;

    // ---- compute: 6-reg rotating window over chunks cbase+15 .. cbase+0 ----
    // XS(j) = tile chunk (2*tid + j), swizzled.
    const int cbase = 2 * tid;
#define XS(j) xs4[SLOT(cbase + (j))]
    {
        float4 r0 = XS(15), r1 = XS(14), r2 = XS(13),
               r3 = XS(12), r4 = XS(11), r5 = XS(10);
        GRP12( 0, r0, r1, r2, r3);  r0 = XS(9);
        GRP12( 1, r1, r2, r3, r4);  r1 = XS(8);
        GRP12( 2, r2, r3, r4, r5);  r2 = XS(7);
        GRP12( 3, r3, r4, r5, r0);  r3 = XS(6);
        GRP12( 4, r4, r5, r0, r1);  r4 = XS(5);
        GRP12( 5, r5, r0, r1, r2);  r5 = XS(4);
        GRP12( 6, r0, r1, r2, r3);  r0 = XS(3);
        GRP12( 7, r1, r2, r3, r4);  r1 = XS(2);
        GRP12( 8, r2, r3, r4, r5);  r2 = XS(1);
        GRP12( 9, r3, r4, r5, r0);  r3 = XS(0);
        GRP12(10, r4, r5, r0, r1);
        GRP12(11, r5, r0, r1, r2);
        GRP12(12, r0, r1, r2, r3);
        GRP12T(13, r1, r2, r3);
    }
#undef XS

    // ---- store 12 outputs ----
    const int ob = o0 + RPT * tid;               // multiple of 12
    if (ob >= 50 && ob + 11 < n_out) {
        float4* o4 = (float4*)(out + ob);        // 16B aligned (ob % 4 == 0)
        o4[0] = make_float4(a0, a1, a2,  a3);
        o4[1] = make_float4(a4, a5, a6,  a7);
        o4[2] = make_float4(a8, a9, a10, a11);
    } else {
        const float accs[RPT] = {a0, a1, a2, a3, a4, a5, a6, a7, a8, a9, a10, a11};
#pragma unroll
        for (int d = 0; d < RPT; ++d) {
            const int o = ob + d;
            if (o >= 50 && o < n_out) out[o] = accs[d];
        }
    }
}

extern "C" void kernel_launch(void* const* d_in, const int* in_sizes, int n_in_arrs,
                              void* d_out, int out_size, void* d_ws, size_t ws_size,
                              hipStream_t stream) {
    const float* x = (const float*)d_in[0];
    const float* h = (const float*)d_in[1];
    const float* b = (const float*)d_in[2];
    float* out = (float*)d_out;
    float* cp  = (float*)d_ws;                        // 3*56*4 = 672 bytes

    const int n_in  = in_sizes[0];                    // 8388608
    const int n_out = (int)((long long)n_in * 3 / 2); // 12582912

    build_coeffs<<<1, 64, 0, stream>>>(h, b, cp);

    const int nblocks = (n_out + OTILE - 1) / OTILE;  // 4096
    fused_fast<<<nblocks, TPB, 0, stream>>>(x, cp, out, n_in, n_out);
    boundary_fix<<<2, 128, 0, stream>>>(x, h, b, out, n_in, n_out, out_size);
}